// Round 14
// baseline (657.044 us; speedup 1.0000x reference)
//
#include <hip/hip_runtime.h>
#include <math.h>

// Boltzmann Gibbs sweep N=8192, single cooperative kernel.
// == r7 (508us) skeleton, ONE structural change: single-barrier phases ==
// Wave0 self-applies the near correction (del(t8-1) x 64-col strip) from
// registers prefetched one phase ahead; the A-section and one barrier per
// phase are deleted. Helpers (waves 1-7) do only the far-pass (rows beyond
// the current sub-block -- disjoint from wave0's rows), ordered by the one
// end-of-phase barrier. Workers and the inter-WG protocol are r7-verbatim.
// Chain: r7's all-VALU form (cmp_f64 -> cndmask -> readlane -> mul/cvt/add);
// the r13 SALU-select variant regressed (VALU<->SALU hazards).
// Decision: u <= sigmoid(s/T) <=> s >= T*log(u/(1-u)); thr fp64,
// POSITION-indexed (lax.scan zips (perm, rand_u)); clamp/state UNIT-indexed.
// All sums fp64; every correction product w*delta is exact in fp32.

#define NN 8192
#define BB 512
#define NBLK 16
#define SUB 64
#define NSUB 8
#define NWG 256
#define NWORK 255
#define TPB 512
#define MAXR 3

typedef unsigned int u32;
typedef unsigned long long u64;

__global__ void k_init(u32* flags, int n) {
  int i = blockIdx.x * blockDim.x + threadIdx.x;
  for (; i < n; i += gridDim.x * blockDim.x) flags[i] = 0;
}

__device__ __forceinline__ u32 ld_rlx(const u32* p) {
  return __hip_atomic_load(p, __ATOMIC_RELAXED, __HIP_MEMORY_SCOPE_AGENT);
}
__device__ __forceinline__ void st_rlx(u32* p, u32 v) {
  __hip_atomic_store(p, v, __ATOMIC_RELAXED, __HIP_MEMORY_SCOPE_AGENT);
}
__device__ __forceinline__ float ldf_rlx(const float* p) {
  return __hip_atomic_load(p, __ATOMIC_RELAXED, __HIP_MEMORY_SCOPE_AGENT);
}
__device__ __forceinline__ void stf_rlx(float* p, float v) {
  __hip_atomic_store(p, v, __ATOMIC_RELAXED, __HIP_MEMORY_SCOPE_AGENT);
}
__device__ __forceinline__ double ldd_rlx(const double* p) {
  return __hip_atomic_load(p, __ATOMIC_RELAXED, __HIP_MEMORY_SCOPE_AGENT);
}
__device__ __forceinline__ void std_rlx(double* p, double v) {
  __hip_atomic_store(p, v, __ATOMIC_RELAXED, __HIP_MEMORY_SCOPE_AGENT);
}

// wave0: load 64x64 diag tile row into registers (m for sub T8N)
#define LOADM(MARR, T8N) do {                                                  \
  const float4* mr_ = (const float4*)(tb + (size_t)((T8N) * SUB + tid) * BB + (T8N) * SUB); \
  _Pragma("unroll")                                                            \
  for (int j_ = 0; j_ < SUB / 4; ++j_) {                                       \
    float4 v_ = mr_[j_];                                                       \
    MARR[4*j_] = v_.x; MARR[4*j_+1] = v_.y;                                    \
    MARR[4*j_+2] = v_.z; MARR[4*j_+3] = v_.w; }                                \
} while (0)

// wave0: prefetch near-strip for phase T8C+1: row (T8C+1)*64+tid, cols T8C*64
#define LOADNV(T8C) do {                                                       \
  const float4* pr_ = (const float4*)(                                         \
      tb + (size_t)(((T8C) + 1) * SUB + tid) * BB + (T8C) * SUB);              \
  _Pragma("unroll")                                                            \
  for (int j_ = 0; j_ < 16; ++j_) nv[j_] = pr_[j_];                            \
} while (0)

// wave0: serial 64-step sub-scan (r7's proven all-VALU form), sum0 as input
#define CHAINX(MARR) do {                                                      \
  double sum_ = sum0, th_ = thrL[row];                                         \
  float dd1_ = d1L[row], dd0_ = d0L[row];                                      \
  float mydel_ = 0.0f;                                                         \
  __builtin_amdgcn_s_setprio(3);                                               \
  _Pragma("unroll")                                                            \
  for (int s_ = 0; s_ < SUB; ++s_) {                                           \
    float down_ = (sum_ >= th_) ? dd1_ : dd0_;                                 \
    float sd_ = __uint_as_float(                                               \
        __builtin_amdgcn_readlane(__float_as_uint(down_), s_));                \
    if (s_ == tid) mydel_ = down_;                                             \
    sum_ += (double)(MARR[s_] * sd_); }                                        \
  __builtin_amdgcn_s_setprio(0);                                               \
  delL[row] = mydel_;                                                          \
  if (pub) stf_rlx(&delG[b * BB + row], mydel_);                               \
} while (0)

__global__ __launch_bounds__(TPB) void k_gibbs(
    const float* __restrict__ w, const float* __restrict__ init,
    const float* __restrict__ clampv, const float* __restrict__ Tp,
    const int* __restrict__ perm, const float* __restrict__ urand,
    float* __restrict__ dout, double* __restrict__ S,
    float* __restrict__ delG, float* __restrict__ tileD,
    u32* subFlag, u32* ack) {
  __shared__ float stateL[NN];                     // workers (32 KB)
  __shared__ double sumsL[BB], thrL[BB];           // WG0 (8 KB)
  __shared__ float d1L[BB], d0L[BB], delL[BB], oldL[BB];
  __shared__ int uL[BB];
  __shared__ double redL[TPB / 64][MAXR];
  const int wg = blockIdx.x, tid = threadIdx.x;
  const int wv = tid >> 6, lane = tid & 63;

  if (wg == 0) {
    // ================= producer: serial scans =================
    double T = (double)Tp[0];
    for (int b = 0; b < NBLK; ++b) {
      const bool pub = (b + 1 < NBLK);
      // per-block tables (independent of workers -> before the wait)
      int pos = b * BB + tid;                      // TPB == BB
      int unit = perm[pos];
      double uu = (double)urand[pos];
      thrL[tid] = T * log(uu / (1.0 - uu));        // u==0 -> -inf -> always 1
      float old = init[unit];
      bool cl = (clampv[unit] != 0.0f);
      d1L[tid] = cl ? 0.0f : (1.0f - old);
      d0L[tid] = cl ? 0.0f : (0.0f - old);
      oldL[tid] = old;
      uL[tid] = unit;
      // wait: all workers acked block b (S[b] fully corrected, tile b in L3)
      {
        const u32* slots = ack + (size_t)b * NWORK;
        for (;;) {
          int ok = 1;
          if (tid < NWORK) ok = (ld_rlx(&slots[tid]) != 0u);
          if (__syncthreads_and(ok)) break;
          __builtin_amdgcn_s_sleep(1);
        }
      }
      sumsL[tid] = ldd_rlx(&S[(size_t)b * BB + tid]);
      __syncthreads();
      const float* tb = tileD + (size_t)b * BB * BB;
      float mA[SUB], mB[SUB];
      float4 nv[16];                               // near-strip prefetch regs
      if (tid < SUB) LOADM(mA, 0);

      for (int t8 = 0; t8 < NSUB; ++t8) {
        if (t8 > 0 && pub && tid == 0)
          st_rlx(&subFlag[b * NSUB + (t8 - 1)], 1u);
        if (tid < SUB) {
          int row = t8 * SUB + tid;
          // near self-apply: del(t8-1) x prefetched strip (register fma)
          double sum0 = sumsL[row];
          if (t8 > 0) {
            int c0 = (t8 - 1) * SUB;
            double na = 0.0;
#pragma unroll
            for (int j = 0; j < 16; ++j) {
              float4 v = nv[j];
              na += (double)(v.x * delL[c0 + 4*j])     + (double)(v.y * delL[c0 + 4*j + 1]) +
                    (double)(v.z * delL[c0 + 4*j + 2]) + (double)(v.w * delL[c0 + 4*j + 3]);
            }
            sum0 += na;
          }
          // issue next-phase prefetches, then run the chain
          if (t8 & 1) {
            if (t8 < NSUB - 1) { LOADM(mA, t8 + 1); LOADNV(t8); }
            CHAINX(mB);
          } else {
            if (t8 < NSUB - 1) { LOADM(mB, t8 + 1); LOADNV(t8); }
            CHAINX(mA);
          }
        } else {
          if (t8 > 0) {
            // far-pass: apply del(t8-1) to rows beyond sub t8 (waves 1-7)
            for (int r = (t8 + 1) * SUB + (tid - SUB); r < BB; r += (TPB - SUB)) {
              int c0 = (t8 - 1) * SUB;
              const float4* mr3 = (const float4*)(tb + (size_t)r * BB + c0);
              double acc = sumsL[r];
#pragma unroll
              for (int j = 0; j < SUB / 4; ++j) {
                float4 v = mr3[j];
                acc += (double)(v.x * delL[c0+4*j])   + (double)(v.y * delL[c0+4*j+1]) +
                       (double)(v.z * delL[c0+4*j+2]) + (double)(v.w * delL[c0+4*j+3]);
              }
              sumsL[r] = acc;
            }
          }
        }
        __syncthreads();                            // ONE barrier per phase
      }
      if (pub && tid == 0) st_rlx(&subFlag[b * NSUB + (NSUB - 1)], 1u);
      dout[uL[tid]] = oldL[tid] + delL[tid];        // exact {0,1} / clamped init
    }
  } else {
    // ================= workers (r7-verbatim) =================
    const int iw = wg - 1;
    const int r0 = (iw * BB) / NWORK, r1 = ((iw + 1) * BB) / NWORK;
    const int cnt = r1 - r0;                        // 2..3
    for (int i = tid; i < NN; i += TPB) stateL[i] = init[i];
    __syncthreads();

    for (int p = 0; p < NBLK; ++p) {
      int pc = perm[p * BB + tid];                  // tile col units
      float g[NSUB];                                // my row's corr strip
      float* tbp = tileD + (size_t)p * BB * BB;

      for (int ri = 0; ri < cnt; ++ri) {
        int unit = perm[p * BB + r0 + ri];
        const float* wrow = w + (size_t)unit * NN;
        const float4* wr4 = (const float4*)wrow;
        const float4* st4 = (const float4*)stateL;
        double acc = 0.0;
#pragma unroll
        for (int k = 0; k < NN / (4 * TPB); ++k) {  // 4 iters
          float4 a = wr4[tid + k * TPB];
          float4 s = st4[tid + k * TPB];
          acc += (double)(a.x * s.x) + (double)(a.y * s.y) +
                 (double)(a.z * s.z) + (double)(a.w * s.w);
        }
        for (int o = 32; o > 0; o >>= 1) acc += __shfl_down(acc, o, 64);
        if (lane == 0) redL[wv][ri] = acc;
        stf_rlx(&tbp[(size_t)(r0 + ri) * BB + tid], wrow[pc]);   // tile row (sc1)
        if (p > 0 && wv == ri) {                    // my row's strip vs block p-1
#pragma unroll
          for (int t8 = 0; t8 < NSUB; ++t8)
            g[t8] = wrow[perm[(p - 1) * BB + t8 * SUB + lane]];
        }
      }
      __syncthreads();
      double Sr = 0.0;
      if (wv < cnt) {
#pragma unroll
        for (int k = 0; k < TPB / 64; ++k) Sr += redL[k][wv];
      }
      if (p > 0) {
        // incremental in-register corrections as sub-dels arrive
        double crr = 0.0;
        for (int t8 = 0; t8 < NSUB; ++t8) {
          const u32* f = &subFlag[(p - 1) * NSUB + t8];
          if (tid == 0) {
            while (ld_rlx(f) == 0u) __builtin_amdgcn_s_sleep(1);
          }
          __syncthreads();
          float dl = ldf_rlx(&delG[(p - 1) * BB + t8 * SUB + lane]);
          if (wv < cnt) crr += (double)(g[t8] * dl);       // exact product
          if (tid < SUB) stateL[perm[(p - 1) * BB + t8 * SUB + tid]] += dl;
        }
        for (int o = 32; o > 0; o >>= 1) crr += __shfl_down(crr, o, 64);
        Sr += crr;
      }
      if (wv < cnt && lane == 0) std_rlx(&S[(size_t)p * BB + r0 + wv], Sr);
      __syncthreads();                              // drain all waves' sc1 stores
      if (tid == 0) st_rlx(&ack[(size_t)p * NWORK + iw], 1u);
    }
  }
}

extern "C" void kernel_launch(void* const* d_in, const int* in_sizes, int n_in,
                              void* d_out, int out_size, void* d_ws, size_t ws_size,
                              hipStream_t stream) {
  const float* w      = (const float*)d_in[0];
  const float* init   = (const float*)d_in[1];
  const float* clampv = (const float*)d_in[2];
  const float* Tp     = (const float*)d_in[3];
  const int*   perm   = (const int*)d_in[4];
  const float* urand  = (const float*)d_in[5];
  float* dout = (float*)d_out;

  double* S    = (double*)d_ws;                        // NN doubles
  float* delG  = (float*)(S + NN);                     // NN
  float* tileD = delG + NN;                            // NBLK*BB*BB (16 MB)
  u32* subFlag = (u32*)(tileD + (size_t)NBLK * BB * BB);  // NBLK*NSUB
  u32* ack     = subFlag + NBLK * NSUB;                   // NBLK*NWORK

  int nflags = NBLK * NSUB + NBLK * NWORK;
  k_init<<<8, 256, 0, stream>>>(subFlag, nflags);

  void* args[] = {(void*)&w, (void*)&init, (void*)&clampv, (void*)&Tp,
                  (void*)&perm, (void*)&urand, (void*)&dout,
                  (void*)&S, (void*)&delG, (void*)&tileD,
                  (void*)&subFlag, (void*)&ack};
  hipLaunchCooperativeKernel((const void*)k_gibbs, dim3(NWG), dim3(TPB),
                             args, 0, stream);
}

// Round 15
// 549.479 us; speedup vs baseline: 1.1958x; 1.1958x over previous
//
#include <hip/hip_runtime.h>
#include <math.h>

// Boltzmann Gibbs sweep N=8192, single cooperative kernel.
// == r7 (508us) VERBATIM except: wave 4 is IDLE (barriers only) ==
// Rationale: waves map to SIMDs as wave%4 -> wave4 shares SIMD0 with wave0's
// serial chain; its near-pass/prefetch/far-pass VALU+LDS issue dilutes the
// chain's issue slots. Near-pass + nv-prefetch move to waves 5-7 + wave 1
// (256 threads, same 4-thr/row layout); far-pass on waves 1-3,5-7 (384 thr).
// 16 blocks of BB=512. WG0 scans block b (8 x 64-step serial sub-scans);
// 255 workers compute panel b+1 dots vs private LDS state + gather diag tile,
// and apply per-sub-del corrections in registers; one ack per worker per block.
// Cross-WG payloads: agent-scope relaxed (sc1) stores; ordering = vmcnt drain
// at __syncthreads + relaxed flag store. No wbl2/inv on the path.
// Decision: u <= sigmoid(s/T) <=> s >= T*log(u/(1-u)); thr fp64,
// POSITION-indexed (lax.scan zips (perm, rand_u)); clamp/state UNIT-indexed.
// All sums fp64; every correction product w*delta is exact in fp32.

#define NN 8192
#define BB 512
#define NBLK 16
#define SUB 64
#define NSUB 8
#define NWG 256
#define NWORK 255
#define TPB 512
#define MAXR 3

typedef unsigned int u32;
typedef unsigned long long u64;

__global__ void k_init(u32* flags, int n) {
  int i = blockIdx.x * blockDim.x + threadIdx.x;
  for (; i < n; i += gridDim.x * blockDim.x) flags[i] = 0;
}

__device__ __forceinline__ u32 ld_rlx(const u32* p) {
  return __hip_atomic_load(p, __ATOMIC_RELAXED, __HIP_MEMORY_SCOPE_AGENT);
}
__device__ __forceinline__ void st_rlx(u32* p, u32 v) {
  __hip_atomic_store(p, v, __ATOMIC_RELAXED, __HIP_MEMORY_SCOPE_AGENT);
}
__device__ __forceinline__ float ldf_rlx(const float* p) {
  return __hip_atomic_load(p, __ATOMIC_RELAXED, __HIP_MEMORY_SCOPE_AGENT);
}
__device__ __forceinline__ void stf_rlx(float* p, float v) {
  __hip_atomic_store(p, v, __ATOMIC_RELAXED, __HIP_MEMORY_SCOPE_AGENT);
}
__device__ __forceinline__ double ldd_rlx(const double* p) {
  return __hip_atomic_load(p, __ATOMIC_RELAXED, __HIP_MEMORY_SCOPE_AGENT);
}
__device__ __forceinline__ void std_rlx(double* p, double v) {
  __hip_atomic_store(p, v, __ATOMIC_RELAXED, __HIP_MEMORY_SCOPE_AGENT);
}

// wave0: load 64x64 diag tile row into registers
#define LOADM(MARR, T8N) do {                                                  \
  const float4* mr_ = (const float4*)(tb + (size_t)((T8N) * SUB + tid) * BB + (T8N) * SUB); \
  _Pragma("unroll")                                                            \
  for (int j_ = 0; j_ < SUB / 4; ++j_) {                                       \
    float4 v_ = mr_[j_];                                                       \
    MARR[4*j_] = v_.x; MARR[4*j_+1] = v_.y;                                    \
    MARR[4*j_+2] = v_.z; MARR[4*j_+3] = v_.w; }                                \
} while (0)

// wave0: serial 64-step sub-scan (r7's proven all-VALU form)
#define CHAIN(MARR, T8C) do {                                                  \
  int row_ = (T8C) * SUB + tid;                                                \
  double sum_ = sumsL[row_], th_ = thrL[row_];                                 \
  float dd1_ = d1L[row_], dd0_ = d0L[row_];                                    \
  float mydel_ = 0.0f;                                                         \
  __builtin_amdgcn_s_setprio(3);                                               \
  _Pragma("unroll")                                                            \
  for (int s_ = 0; s_ < SUB; ++s_) {                                           \
    float down_ = (sum_ >= th_) ? dd1_ : dd0_;                                 \
    float sd_ = __uint_as_float(                                               \
        __builtin_amdgcn_readlane(__float_as_uint(down_), s_));                \
    if (s_ == tid) mydel_ = down_;                                             \
    sum_ += (double)(MARR[s_] * sd_); }                                        \
  __builtin_amdgcn_s_setprio(0);                                               \
  delL[row_] = mydel_;                                                         \
  if (pub) stf_rlx(&delG[b * BB + row_], mydel_);                              \
} while (0)

__global__ __launch_bounds__(TPB) void k_gibbs(
    const float* __restrict__ w, const float* __restrict__ init,
    const float* __restrict__ clampv, const float* __restrict__ Tp,
    const int* __restrict__ perm, const float* __restrict__ urand,
    float* __restrict__ dout, double* __restrict__ S,
    float* __restrict__ delG, float* __restrict__ tileD,
    u32* subFlag, u32* ack) {
  __shared__ float stateL[NN];                     // workers (32 KB)
  __shared__ double sumsL[BB], thrL[BB];           // WG0 (8 KB)
  __shared__ float d1L[BB], d0L[BB], delL[BB], oldL[BB];
  __shared__ int uL[BB];
  __shared__ double redL[TPB / 64][MAXR];
  const int wg = blockIdx.x, tid = threadIdx.x;
  const int wv = tid >> 6, lane = tid & 63;

  if (wg == 0) {
    // ================= producer: serial scans =================
    double T = (double)Tp[0];
    for (int b = 0; b < NBLK; ++b) {
      const bool pub = (b + 1 < NBLK);
      // per-block tables (independent of workers -> before the wait)
      int pos = b * BB + tid;                      // TPB == BB
      int unit = perm[pos];
      double uu = (double)urand[pos];
      thrL[tid] = T * log(uu / (1.0 - uu));        // u==0 -> -inf -> always 1
      float old = init[unit];
      bool cl = (clampv[unit] != 0.0f);
      d1L[tid] = cl ? 0.0f : (1.0f - old);
      d0L[tid] = cl ? 0.0f : (0.0f - old);
      oldL[tid] = old;
      uL[tid] = unit;
      // wait: all workers acked block b (S[b] fully corrected, tile b in L3)
      {
        const u32* slots = ack + (size_t)b * NWORK;
        for (;;) {
          int ok = 1;
          if (tid < NWORK) ok = (ld_rlx(&slots[tid]) != 0u);
          if (__syncthreads_and(ok)) break;
          __builtin_amdgcn_s_sleep(1);
        }
      }
      sumsL[tid] = ldd_rlx(&S[(size_t)b * BB + tid]);
      __syncthreads();
      const float* tb = tileD + (size_t)b * BB * BB;
      float mA[SUB], mB[SUB];
      float4 nv0, nv1, nv2, nv3;                   // near-strip prefetch regs
      // near/prefetch thread id: waves 5-7 -> 0..191, wave 1 -> 192..255
      const int nt = (tid >= 320) ? (tid - 320)
                   : ((tid >= 64 && tid < 128) ? 192 + (tid - 64) : -1);
      // far-pass thread id: waves 1-3 -> 0..191, waves 5-7 -> 192..383
      const int ft = (tid >= 320) ? (tid - 320 + 192)
                   : ((tid >= 64 && tid < 256) ? (tid - 64) : -1);
      if (tid < SUB) LOADM(mA, 0);

      for (int t8 = 0; t8 < NSUB; ++t8) {
        // ---- A section: publish del(t8-1) flag + register near-fma ----
        if (t8 > 0) {
          if (pub && tid == 0) st_rlx(&subFlag[b * NSUB + (t8 - 1)], 1u);
          if (nt >= 0) {
            int rrow = t8 * SUB + (nt >> 2);
            int q = nt & 3;
            int c0 = (t8 - 1) * SUB + q * 16;
            double p_ =
                (double)(nv0.x * delL[c0])    + (double)(nv0.y * delL[c0+1]) +
                (double)(nv0.z * delL[c0+2])  + (double)(nv0.w * delL[c0+3]) +
                (double)(nv1.x * delL[c0+4])  + (double)(nv1.y * delL[c0+5]) +
                (double)(nv1.z * delL[c0+6])  + (double)(nv1.w * delL[c0+7]);
            p_ +=
                (double)(nv2.x * delL[c0+8])  + (double)(nv2.y * delL[c0+9]) +
                (double)(nv2.z * delL[c0+10]) + (double)(nv2.w * delL[c0+11]) +
                (double)(nv3.x * delL[c0+12]) + (double)(nv3.y * delL[c0+13]) +
                (double)(nv3.z * delL[c0+14]) + (double)(nv3.w * delL[c0+15]);
            p_ += __shfl_down(p_, 2, 4);
            p_ += __shfl_down(p_, 1, 4);
            if (q == 0) sumsL[rrow] += p_;
          }
        }
        __syncthreads();
        // ---- B section: chain || prefetch || far-pass (wave 4 idle) ----
        if (tid < SUB) {
          if (t8 & 1) { if (t8 < NSUB - 1) LOADM(mA, t8 + 1); CHAIN(mB, t8); }
          else        { if (t8 < NSUB - 1) LOADM(mB, t8 + 1); CHAIN(mA, t8); }
        } else {
          if (t8 < NSUB - 1 && nt >= 0) {
            // prefetch near-strip: rows sub(t8+1), cols sub(t8)
            const float4* pr = (const float4*)(
                tb + (size_t)((t8 + 1) * SUB + (nt >> 2)) * BB + t8 * SUB + (nt & 3) * 16);
            nv0 = pr[0]; nv1 = pr[1]; nv2 = pr[2]; nv3 = pr[3];
          }
          if (t8 > 0 && ft >= 0) {
            // far-pass: apply del(t8-1) to rows beyond sub t8
            for (int r = (t8 + 1) * SUB + ft; r < BB; r += 384) {
              int c0 = (t8 - 1) * SUB;
              const float4* mr3 = (const float4*)(tb + (size_t)r * BB + c0);
              double acc = sumsL[r];
#pragma unroll
              for (int j = 0; j < SUB / 4; ++j) {
                float4 v = mr3[j];
                acc += (double)(v.x * delL[c0+4*j])   + (double)(v.y * delL[c0+4*j+1]) +
                       (double)(v.z * delL[c0+4*j+2]) + (double)(v.w * delL[c0+4*j+3]);
              }
              sumsL[r] = acc;
            }
          }
        }
        __syncthreads();                            // drains delG stores (vmcnt)
      }
      if (pub && tid == 0) st_rlx(&subFlag[b * NSUB + (NSUB - 1)], 1u);
      dout[uL[tid]] = oldL[tid] + delL[tid];        // exact {0,1} / clamped init
    }
  } else {
    // ================= workers (r7-verbatim) =================
    const int iw = wg - 1;
    const int r0 = (iw * BB) / NWORK, r1 = ((iw + 1) * BB) / NWORK;
    const int cnt = r1 - r0;                        // 2..3
    for (int i = tid; i < NN; i += TPB) stateL[i] = init[i];
    __syncthreads();

    for (int p = 0; p < NBLK; ++p) {
      int pc = perm[p * BB + tid];                  // tile col units
      float g[NSUB];                                // my row's corr strip
      float* tbp = tileD + (size_t)p * BB * BB;

      for (int ri = 0; ri < cnt; ++ri) {
        int unit = perm[p * BB + r0 + ri];
        const float* wrow = w + (size_t)unit * NN;
        const float4* wr4 = (const float4*)wrow;
        const float4* st4 = (const float4*)stateL;
        double acc = 0.0;
#pragma unroll
        for (int k = 0; k < NN / (4 * TPB); ++k) {  // 4 iters
          float4 a = wr4[tid + k * TPB];
          float4 s = st4[tid + k * TPB];
          acc += (double)(a.x * s.x) + (double)(a.y * s.y) +
                 (double)(a.z * s.z) + (double)(a.w * s.w);
        }
        for (int o = 32; o > 0; o >>= 1) acc += __shfl_down(acc, o, 64);
        if (lane == 0) redL[wv][ri] = acc;
        stf_rlx(&tbp[(size_t)(r0 + ri) * BB + tid], wrow[pc]);   // tile row (sc1)
        if (p > 0 && wv == ri) {                    // my row's strip vs block p-1
#pragma unroll
          for (int t8 = 0; t8 < NSUB; ++t8)
            g[t8] = wrow[perm[(p - 1) * BB + t8 * SUB + lane]];
        }
      }
      __syncthreads();
      double Sr = 0.0;
      if (wv < cnt) {
#pragma unroll
        for (int k = 0; k < TPB / 64; ++k) Sr += redL[k][wv];
      }
      if (p > 0) {
        // incremental in-register corrections as sub-dels arrive
        double crr = 0.0;
        for (int t8 = 0; t8 < NSUB; ++t8) {
          const u32* f = &subFlag[(p - 1) * NSUB + t8];
          if (tid == 0) {
            while (ld_rlx(f) == 0u) __builtin_amdgcn_s_sleep(1);
          }
          __syncthreads();
          float dl = ldf_rlx(&delG[(p - 1) * BB + t8 * SUB + lane]);
          if (wv < cnt) crr += (double)(g[t8] * dl);       // exact product
          if (tid < SUB) stateL[perm[(p - 1) * BB + t8 * SUB + tid]] += dl;
        }
        for (int o = 32; o > 0; o >>= 1) crr += __shfl_down(crr, o, 64);
        Sr += crr;
      }
      if (wv < cnt && lane == 0) std_rlx(&S[(size_t)p * BB + r0 + wv], Sr);
      __syncthreads();                              // drain all waves' sc1 stores
      if (tid == 0) st_rlx(&ack[(size_t)p * NWORK + iw], 1u);
    }
  }
}

extern "C" void kernel_launch(void* const* d_in, const int* in_sizes, int n_in,
                              void* d_out, int out_size, void* d_ws, size_t ws_size,
                              hipStream_t stream) {
  const float* w      = (const float*)d_in[0];
  const float* init   = (const float*)d_in[1];
  const float* clampv = (const float*)d_in[2];
  const float* Tp     = (const float*)d_in[3];
  const int*   perm   = (const int*)d_in[4];
  const float* urand  = (const float*)d_in[5];
  float* dout = (float*)d_out;

  double* S    = (double*)d_ws;                        // NN doubles
  float* delG  = (float*)(S + NN);                     // NN
  float* tileD = delG + NN;                            // NBLK*BB*BB (16 MB)
  u32* subFlag = (u32*)(tileD + (size_t)NBLK * BB * BB);  // NBLK*NSUB
  u32* ack     = subFlag + NBLK * NSUB;                   // NBLK*NWORK

  int nflags = NBLK * NSUB + NBLK * NWORK;
  k_init<<<8, 256, 0, stream>>>(subFlag, nflags);

  void* args[] = {(void*)&w, (void*)&init, (void*)&clampv, (void*)&Tp,
                  (void*)&perm, (void*)&urand, (void*)&dout,
                  (void*)&S, (void*)&delG, (void*)&tileD,
                  (void*)&subFlag, (void*)&ack};
  hipLaunchCooperativeKernel((const void*)k_gibbs, dim3(NWG), dim3(TPB),
                             args, 0, stream);
}